// Round 1
// baseline (660.246 us; speedup 1.0000x reference)
//
#include <hip/hip_runtime.h>
#include <hip/hip_bf16.h>

#define NBINS 32
#define DIM 64
#define NKNOT 33                    // NBINS + 1
#define RANGE_MIN_F (-5.0f)

// knot workspace layout in d_ws (floats):
//   kx: [DIM][NKNOT]  at offset 0
//   ky: [DIM][NKNOT]  at offset DIM*NKNOT
//   kd: [DIM][NKNOT]  at offset 2*DIM*NKNOT
#define KTAB (DIM * NKNOT)          // 2112 floats per table

// ---------------------------------------------------------------------------
// Kernel 1: build knot tables (cumsum of widths/heights + slope padding).
// One block, one thread per dimension. Sequential fp32 cumsum matches the
// numpy reference accumulation order.
// ---------------------------------------------------------------------------
__global__ void rqs_precompute_knots(const float* __restrict__ bw,
                                     const float* __restrict__ bh,
                                     const float* __restrict__ ks,
                                     float* __restrict__ knots) {
    int d = threadIdx.x;
    if (d >= DIM) return;
    float* kx = knots;
    float* ky = knots + KTAB;
    float* kd = knots + 2 * KTAB;

    float acc = 0.0f;
    kx[d * NKNOT + 0] = RANGE_MIN_F;
    for (int k = 0; k < NBINS; ++k) {
        acc += bw[d * NBINS + k];
        kx[d * NKNOT + k + 1] = RANGE_MIN_F + acc;
    }
    acc = 0.0f;
    ky[d * NKNOT + 0] = RANGE_MIN_F;
    for (int k = 0; k < NBINS; ++k) {
        acc += bh[d * NBINS + k];
        ky[d * NKNOT + k + 1] = RANGE_MIN_F + acc;
    }
    kd[d * NKNOT + 0] = 1.0f;
    for (int k = 0; k < NBINS - 1; ++k)
        kd[d * NKNOT + k + 1] = ks[d * (NBINS - 1) + k];
    kd[d * NKNOT + NBINS] = 1.0f;
}

// ---------------------------------------------------------------------------
// Kernel 2: evaluate the spline. One element per thread per iteration,
// ELEMS iterations strided by total thread count (stride % 64 == 0, so each
// thread's dimension d is fixed). Knot tables staged in LDS; stride-33 rows
// give conflict-free (2-way, free on wave64) bank access.
// ---------------------------------------------------------------------------
#define BLOCK 256
#define ELEMS 4

__global__ __launch_bounds__(BLOCK) void rqs_eval(
        const float* __restrict__ x,
        const float* __restrict__ knots,
        float* __restrict__ out,
        int total) {                    // total = N*D
    __shared__ float s_kx[KTAB];
    __shared__ float s_ky[KTAB];
    __shared__ float s_kd[KTAB];

    // cooperative LDS fill
    for (int j = threadIdx.x; j < KTAB; j += BLOCK) {
        s_kx[j] = knots[j];
        s_ky[j] = knots[KTAB + j];
        s_kd[j] = knots[2 * KTAB + j];
    }
    __syncthreads();

    const int tid    = blockIdx.x * BLOCK + threadIdx.x;
    const int stride = gridDim.x * BLOCK;       // multiple of 64
    const int d      = tid & (DIM - 1);
    const float* kxd = &s_kx[d * NKNOT];
    const float* kyd = &s_ky[d * NKNOT];
    const float* kdd = &s_kd[d * NKNOT];
    const float kx_last = kxd[NBINS];

    #pragma unroll
    for (int e = 0; e < ELEMS; ++e) {
        int i = tid + e * stride;
        if (i >= total) break;
        float xv = x[i];

        // binary search: largest p in [0,31] with kx[p] <= xv
        int p = 0;
        #pragma unroll
        for (int s = 16; s >= 1; s >>= 1) {
            p += (kxd[p + s] <= xv) ? s : 0;
        }

        float xk  = kxd[p];
        float xk1 = kxd[p + 1];
        float yk  = kyd[p];
        float yk1 = kyd[p + 1];
        float dk  = kdd[p];
        float dk1 = kdd[p + 1];

        float w  = xk1 - xk;
        float h  = yk1 - yk;
        float rw = __builtin_amdgcn_rcpf(w);
        float sm = h * rw;                  // mean slope
        float t  = (xv - xk) * rw;
        float tt = t * (1.0f - t);
        float num = h * (sm * t * t + dk * tt);
        float den = sm + (dk1 + dk - 2.0f * sm) * tt;
        float y   = yk + num * __builtin_amdgcn_rcpf(den);

        bool inside = (xv >= RANGE_MIN_F) && (xv <= kx_last);
        out[i] = inside ? y : xv;
    }
}

extern "C" void kernel_launch(void* const* d_in, const int* in_sizes, int n_in,
                              void* d_out, int out_size, void* d_ws, size_t ws_size,
                              hipStream_t stream) {
    const float* x  = (const float*)d_in[0];
    const float* bw = (const float*)d_in[1];
    const float* bh = (const float*)d_in[2];
    const float* ks = (const float*)d_in[3];
    float* out   = (float*)d_out;
    float* knots = (float*)d_ws;          // 3*KTAB floats = 25,344 B

    const int total = out_size;           // N*D = 1<<26

    rqs_precompute_knots<<<1, DIM, 0, stream>>>(bw, bh, ks, knots);

    const int threads_needed = (total + ELEMS - 1) / ELEMS;
    const int grid = (threads_needed + BLOCK - 1) / BLOCK;
    rqs_eval<<<grid, BLOCK, 0, stream>>>(x, knots, out, total);
}

// Round 2
// 467.843 us; speedup vs baseline: 1.4113x; 1.4113x over previous
//
#include <hip/hip_runtime.h>
#include <hip/hip_bf16.h>

#define NBINS 32
#define DIM 64
#define NKNOT 33
#define RANGE_MIN_F (-5.0f)
#define RANGE_MAX_F (5.0f)
#define NCELL 64                       // LUT cells over [range_min, range_max]
#define LUT_STRIDE 68                  // bytes per dim row; (17d + g/4) % 32 banks -> uniform

#define BLOCK 1024
#define GRID 512                       // persistent: 2 blocks/CU on 256 CUs
#define ELEMS 4                        // inner ILP unroll

// LDS budget per block:
//   s_kx   64*33*4  = 8448 B   (stride-33 rows: bank (d+p)%32, uniform over lanes)
//   s_kd   64*33*4  = 8448 B
//   s_recA 64*32*16 = 32768 B  ({xk, 1/w, yk, h}; index swizzled by (p+d)&31)
//   s_lut  64*68    = 4352 B
//   total ~52.75 KB -> 2 blocks/CU = 105.5 KB of 160 KB, 32 waves/CU

__global__ __launch_bounds__(BLOCK, 8) void rqs_fused(
        const float* __restrict__ x,
        const float* __restrict__ bw,
        const float* __restrict__ bh,
        const float* __restrict__ ks,
        float* __restrict__ out,
        int total) {
    __shared__ float  s_kx[DIM * NKNOT];
    __shared__ float  s_kd[DIM * NKNOT];
    __shared__ float4 s_recA[DIM * NBINS];
    __shared__ unsigned char s_lut[DIM * LUT_STRIDE];

    const int t = threadIdx.x;
    float* ra = (float*)s_recA;

    // ---- phase 1: build knot rows + records (3 groups of 64 threads) ----
    if (t < 64) {
        // widths: kx row + recA.{x,y} = {xk, 1/w}
        const int d = t;
        float acc = 0.0f;
        s_kx[d * NKNOT + 0] = RANGE_MIN_F;
        #pragma unroll
        for (int k = 0; k < NBINS; ++k) {
            float w = bw[d * NBINS + k];
            int idx = d * NBINS + ((k + d) & (NBINS - 1));   // swizzled record slot
            ra[idx * 4 + 0] = RANGE_MIN_F + acc;             // xk
            ra[idx * 4 + 1] = __builtin_amdgcn_rcpf(w);      // 1/w
            acc += w;
            s_kx[d * NKNOT + k + 1] = RANGE_MIN_F + acc;
        }
    } else if (t < 128) {
        // heights: recA.{z,w} = {yk, h}
        const int d = t - 64;
        float acc = 0.0f;
        #pragma unroll
        for (int k = 0; k < NBINS; ++k) {
            float h = bh[d * NBINS + k];
            int idx = d * NBINS + ((k + d) & (NBINS - 1));
            ra[idx * 4 + 2] = RANGE_MIN_F + acc;             // yk
            ra[idx * 4 + 3] = h;
            acc += h;
        }
    } else if (t < 192) {
        // slopes row: kd = [1, ks..., 1]
        const int d = t - 128;
        s_kd[d * NKNOT + 0] = 1.0f;
        #pragma unroll
        for (int k = 0; k < NBINS - 1; ++k)
            s_kd[d * NKNOT + k + 1] = ks[d * (NBINS - 1) + k];
        s_kd[d * NKNOT + NBINS] = 1.0f;
    }
    __syncthreads();

    // ---- phase 2: LUT build: lut[d][g] = max{p in [0,31] : kx[p] <= cellLeft(g)} ----
    const float cellw = (RANGE_MAX_F - RANGE_MIN_F) / (float)NCELL;
    #pragma unroll
    for (int e = 0; e < (DIM * NCELL + BLOCK - 1) / BLOCK; ++e) {
        int j = t + e * BLOCK;
        if (j < DIM * NCELL) {
            int d = j >> 6, g = j & (NCELL - 1);
            float cl = RANGE_MIN_F + (float)g * cellw;
            int p = 0;
            #pragma unroll
            for (int s = 16; s >= 1; s >>= 1)
                p += (s_kx[d * NKNOT + p + s] <= cl) ? s : 0;
            s_lut[d * LUT_STRIDE + g] = (unsigned char)p;
        }
    }
    __syncthreads();

    // ---- phase 3: evaluate (persistent grid-stride, d fixed per thread) ----
    const int tid = blockIdx.x * BLOCK + t;
    const int TOT = GRID * BLOCK;                  // multiple of 64 -> d invariant
    const int d   = tid & (DIM - 1);
    const float* kxd = s_kx + d * NKNOT;
    const float* kdd = s_kd + d * NKNOT;
    const unsigned char* lutd = s_lut + d * LUT_STRIDE;
    const float kx_last = kxd[NBINS];
    const float inv_cw = (float)NCELL / (RANGE_MAX_F - RANGE_MIN_F);

    for (int base = tid; base < total; base += TOT * ELEMS) {
        #pragma unroll
        for (int e = 0; e < ELEMS; ++e) {
            int i = base + e * TOT;
            if (i >= total) break;
            float xv = x[i];

            int g = (int)((xv - RANGE_MIN_F) * inv_cw);
            g = min(max(g, 0), NCELL - 1);
            int p = (int)lutd[g];
            // upward fixup (expected <=1 iter; bins ~3x cell width)
            while (p < NBINS - 1 && kxd[p + 1] <= xv) ++p;

            float4 r = s_recA[d * NBINS + ((p + d) & (NBINS - 1))];
            float dk  = kdd[p];
            float dk1 = kdd[p + 1];

            float rw = r.y;
            float h  = r.w;
            float sm = h * rw;
            float tt0 = (xv - r.x) * rw;
            float tt  = tt0 * (1.0f - tt0);
            float num = h * (sm * tt0 * tt0 + dk * tt);
            float den = sm + (dk1 + dk - 2.0f * sm) * tt;
            float y   = r.z + num * __builtin_amdgcn_rcpf(den);

            bool inside = (xv >= RANGE_MIN_F) && (xv <= kx_last);
            out[i] = inside ? y : xv;
        }
    }
}

extern "C" void kernel_launch(void* const* d_in, const int* in_sizes, int n_in,
                              void* d_out, int out_size, void* d_ws, size_t ws_size,
                              hipStream_t stream) {
    const float* x  = (const float*)d_in[0];
    const float* bw = (const float*)d_in[1];
    const float* bh = (const float*)d_in[2];
    const float* ks = (const float*)d_in[3];
    float* out = (float*)d_out;

    rqs_fused<<<GRID, BLOCK, 0, stream>>>(x, bw, bh, ks, out, out_size);
}